// Round 2
// baseline (3472.099 us; speedup 1.0000x reference)
//
#include <hip/hip_runtime.h>
#include <math.h>

#define N_GRAPHS 200000
#define NODES_PER_GRAPH 37
#define NTOT (N_GRAPHS * NODES_PER_GRAPH)   /* 7,400,000 */
#define NEDGE (8 * NTOT)                    /* 59,200,000 */

// ---------------------------------------------------------------------------
// Kernel 1: per-edge MLP + gather + scatter-add
//   ew  = b2 + sum_j relu(ea*W1[j] + b1[j]) * W2[j]
//   atomicAdd(agg[dst], x[src] * ew)
// 4 edges per thread, vectorized index/attr loads.
// ---------------------------------------------------------------------------
__global__ __launch_bounds__(256) void edge_kernel(
    const float* __restrict__ x,
    const float* __restrict__ edge_attr,
    const int*   __restrict__ edge_index,   // [2, E]: src at [0,E), dst at [E,2E)
    const float* __restrict__ W1, const float* __restrict__ b1,
    const float* __restrict__ W2, const float* __restrict__ b2,
    float* __restrict__ agg)
{
    // Wave-uniform weight loads -> scalar regs
    const float w10 = W1[0], w11 = W1[1], w12 = W1[2], w13 = W1[3];
    const float b10 = b1[0], b11 = b1[1], b12 = b1[2], b13 = b1[3];
    const float w20 = W2[0], w21 = W2[1], w22 = W2[2], w23 = W2[3];
    const float b20 = b2[0];

    long long t  = (long long)blockIdx.x * blockDim.x + threadIdx.x;
    long long e0 = t * 4;
    if (e0 >= NEDGE) return;   // NEDGE % 4 == 0, so full quad when in range

    int4   s  = *(const int4*)  (edge_index + e0);
    int4   d  = *(const int4*)  (edge_index + (long long)NEDGE + e0);
    float4 ea = *(const float4*)(edge_attr  + e0);

    float eav[4] = {ea.x, ea.y, ea.z, ea.w};
    int   sv[4]  = {s.x, s.y, s.z, s.w};
    int   dv[4]  = {d.x, d.y, d.z, d.w};

    float msg[4];
    #pragma unroll
    for (int i = 0; i < 4; ++i) {
        float a  = eav[i];
        float h0 = fmaxf(fmaf(a, w10, b10), 0.f);
        float h1 = fmaxf(fmaf(a, w11, b11), 0.f);
        float h2 = fmaxf(fmaf(a, w12, b12), 0.f);
        float h3 = fmaxf(fmaf(a, w13, b13), 0.f);
        float ew = fmaf(h0, w20, fmaf(h1, w21, fmaf(h2, w22, fmaf(h3, w23, b20))));
        msg[i] = x[sv[i]] * ew;
    }
    #pragma unroll
    for (int i = 0; i < 4; ++i) {
        atomicAdd(&agg[dv[i]], msg[i]);
    }
}

// ---------------------------------------------------------------------------
// Kernel 2: per-graph head.
//   nodes = agg + x*root + conv_bias  (staged coalesced into LDS)
//   h = relu(nodes @ Wa + ba); h = relu(h @ Wb + bb); res = h @ Wc + bc
//   angle = atan(X/Y) + pi/2*sign(Y) + pi;  out = angle * 12/(2pi)
// 256 graphs per block, one thread per graph.
// ---------------------------------------------------------------------------
__global__ __launch_bounds__(256) void graph_kernel(
    const float* __restrict__ agg,
    const float* __restrict__ x,
    const float* __restrict__ rootp,
    const float* __restrict__ conv_bias,
    const float* __restrict__ Wa, const float* __restrict__ ba,
    const float* __restrict__ Wb, const float* __restrict__ bb,
    const float* __restrict__ Wc, const float* __restrict__ bc,
    float* __restrict__ out)
{
    __shared__ float s_nodes[256 * NODES_PER_GRAPH];  // 37888 B
    __shared__ float s_Wa[37 * 8];                    // 296 entries!
    __shared__ float s_ba[8];
    __shared__ float s_Wb[64];
    __shared__ float s_bb[8];
    __shared__ float s_Wc[16];
    __shared__ float s_bc[2];

    const int tid = threadIdx.x;
    const float root = rootp[0];
    const float cb   = conv_bias[0];

    // NOTE: 296 > blockDim(256) -> must stride. (Round-1 bug: tail of Wa
    // was uninitialized LDS.)
    for (int i = tid; i < 37 * 8; i += 256) s_Wa[i] = Wa[i];
    if (tid < 64)  s_Wb[tid] = Wb[tid];
    if (tid < 16)  s_Wc[tid] = Wc[tid];
    if (tid < 8)   { s_ba[tid] = ba[tid]; s_bb[tid] = bb[tid]; }
    if (tid < 2)   s_bc[tid] = bc[tid];

    const long long base = (long long)blockIdx.x * 256 * NODES_PER_GRAPH;
    int count = 256 * NODES_PER_GRAPH;
    if (base + count > (long long)NTOT) count = (int)((long long)NTOT - base);
    for (int i = tid; i < count; i += 256) {
        long long gi = base + i;
        s_nodes[i] = fmaf(root, x[gi], agg[gi]) + cb;
    }
    __syncthreads();

    const int g = blockIdx.x * 256 + tid;
    if (g >= N_GRAPHS) return;

    const float* nd = s_nodes + tid * NODES_PER_GRAPH;

    float h1[8];
    #pragma unroll
    for (int j = 0; j < 8; ++j) h1[j] = s_ba[j];
    #pragma unroll 4
    for (int k = 0; k < NODES_PER_GRAPH; ++k) {
        float nv = nd[k];
        #pragma unroll
        for (int j = 0; j < 8; ++j) h1[j] = fmaf(nv, s_Wa[k * 8 + j], h1[j]);
    }
    #pragma unroll
    for (int j = 0; j < 8; ++j) h1[j] = fmaxf(h1[j], 0.f);

    float h2[8];
    #pragma unroll
    for (int j = 0; j < 8; ++j) {
        float acc = s_bb[j];
        #pragma unroll
        for (int k = 0; k < 8; ++k) acc = fmaf(h1[k], s_Wb[k * 8 + j], acc);
        h2[j] = fmaxf(acc, 0.f);
    }

    float X = s_bc[0], Y = s_bc[1];
    #pragma unroll
    for (int k = 0; k < 8; ++k) {
        X = fmaf(h2[k], s_Wc[k * 2 + 0], X);
        Y = fmaf(h2[k], s_Wc[k * 2 + 1], Y);
    }

    const float PI      = 3.14159265358979323846f;
    const float HALF_PI = 1.57079632679489661923f;
    float sgn   = (Y > 0.f) ? 1.f : ((Y < 0.f) ? -1.f : 0.f);
    float angle = atanf(X / Y) + HALF_PI * sgn + PI;
    out[g] = angle * (12.0f / (2.0f * PI));
}

extern "C" void kernel_launch(void* const* d_in, const int* in_sizes, int n_in,
                              void* d_out, int out_size, void* d_ws, size_t ws_size,
                              hipStream_t stream) {
    const float* x         = (const float*)d_in[0];
    const float* edge_attr = (const float*)d_in[1];
    const float* W1        = (const float*)d_in[2];
    const float* b1        = (const float*)d_in[3];
    const float* W2        = (const float*)d_in[4];
    const float* b2        = (const float*)d_in[5];
    const float* root      = (const float*)d_in[6];
    const float* conv_bias = (const float*)d_in[7];
    const float* Wa        = (const float*)d_in[8];
    const float* ba        = (const float*)d_in[9];
    const float* Wb        = (const float*)d_in[10];
    const float* bb        = (const float*)d_in[11];
    const float* Wc        = (const float*)d_in[12];
    const float* bc        = (const float*)d_in[13];
    const int*   edge_index= (const int*)d_in[14];
    // d_in[15] = batch_size (compile-time constant here)

    float* agg = (float*)d_ws;   // NTOT floats = 29.6 MB
    hipMemsetAsync(agg, 0, (size_t)NTOT * sizeof(float), stream);

    const int threads = 256;
    const long long quads = (NEDGE + 3) / 4;
    const int blocksB = (int)((quads + threads - 1) / threads);
    edge_kernel<<<blocksB, threads, 0, stream>>>(x, edge_attr, edge_index,
                                                 W1, b1, W2, b2, agg);

    const int blocksC = (N_GRAPHS + threads - 1) / threads;
    graph_kernel<<<blocksC, threads, 0, stream>>>(agg, x, root, conv_bias,
                                                  Wa, ba, Wb, bb, Wc, bc,
                                                  (float*)d_out);
}